// Round 9
// baseline (229.427 us; speedup 1.0000x reference)
//
#include <hip/hip_runtime.h>
#include <hip/hip_bf16.h>

// R9 = CONTROL ROUND. Product kernels byte-identical to R8 (138.5 us).
// Appended stream_kernel reads all of K with the SAME access pattern as
// fused_kernel (8192 wave-cursors x 128 contiguous rows, NT f32x4, same
// grid/occupancy) but zero compute/shfl/stores. T_stream = dur - 138.5.

#define QUERY_DIM 128
#define HIDDEN 128

typedef float f32x4 __attribute__((ext_vector_type(4)));

__device__ __forceinline__ float dot4(f32x4 a, f32x4 b) {
    return a.x * b.x + a.y * b.y + a.z * b.z + a.w * b.w;
}

// ---------------------------------------------------------------------------
// Kernel 1 (combo): blocks 0..63  -> W[e][d] = sum_h WQ[h][e]*WK[h][d]
//                   blocks 64..   -> segment starts via binary search
// ---------------------------------------------------------------------------
__global__ __launch_bounds__(256) void combo_kernel(const float* __restrict__ WQ,
                                                    const float* __restrict__ WK,
                                                    float* __restrict__ W,
                                                    const int* __restrict__ idx,
                                                    int* __restrict__ start,
                                                    int nmols, int total) {
    int b = blockIdx.x;
    int t = threadIdx.x;
    if (b < 64) {
        int e = b * 2 + (t >> 7);   // 0..127
        int d = t & 127;
        float acc = 0.f;
#pragma unroll 8
        for (int h = 0; h < HIDDEN; ++h) {
            acc += WQ[h * QUERY_DIM + e] * WK[h * 128 + d];
        }
        W[e * 128 + d] = acc;
    } else {
        int m = (b - 64) * 256 + t;
        if (m > nmols) return;
        if (m == nmols) { start[m] = total; return; }
        int lo = 0, hi = total;
        while (lo < hi) {
            int mid = (lo + hi) >> 1;
            if (idx[mid] < m) lo = mid + 1; else hi = mid;
        }
        start[m] = lo;
    }
}

// ---------------------------------------------------------------------------
// Kernel 2: R = query @ W.  16 rows/block, 256 threads, d tiled by 4.
// ---------------------------------------------------------------------------
__global__ __launch_bounds__(256) void qproj_kernel(const float* __restrict__ Q,
                                                    const float* __restrict__ W,
                                                    float* __restrict__ R, int nmols) {
    __shared__ float wl[64 * 128];  // 32 KB (half of W)
    __shared__ float ql[16 * 128];  // 8 KB (16 query rows)
    int t = threadIdx.x;
    int c = t & 127;
    int g = t >> 7;
    long row0 = (long)blockIdx.x * 16;

    for (int i = t * 4; i < 16 * 128; i += 256 * 4) {
        *(float4*)&ql[i] = *(const float4*)&Q[row0 * QUERY_DIM + i];
    }

    float acc[8] = {0.f, 0.f, 0.f, 0.f, 0.f, 0.f, 0.f, 0.f};

    for (int half = 0; half < 2; ++half) {
        __syncthreads();
        for (int i = t * 4; i < 64 * 128; i += 256 * 4) {
            *(float4*)&wl[i] = *(const float4*)&W[half * 64 * 128 + i];
        }
        __syncthreads();
        for (int d = 0; d < 64; d += 4) {
            float w0 = wl[(d + 0) * 128 + c];
            float w1 = wl[(d + 1) * 128 + c];
            float w2 = wl[(d + 2) * 128 + c];
            float w3 = wl[(d + 3) * 128 + c];
            int dg = half * 64 + d;
#pragma unroll
            for (int r = 0; r < 8; ++r) {
                f32x4 q = *(const f32x4*)&ql[(g * 8 + r) * 128 + dg];
                acc[r] += q.x * w0 + q.y * w1 + q.z * w2 + q.w * w3;
            }
        }
    }
#pragma unroll
    for (int r = 0; r < 8; ++r) {
        long row = row0 + g * 8 + r;
        if (row < nmols) R[row * 128 + c] = acc[r];
    }
}

// ---------------------------------------------------------------------------
// Kernel 3 (fused, dominant) — byte-identical to R8.
// ---------------------------------------------------------------------------
__global__ __launch_bounds__(256) void fused_kernel(const float* __restrict__ K,
                                                    const float* __restrict__ R,
                                                    const int* __restrict__ start,
                                                    float* __restrict__ weights,
                                                    float* scores,   // no restrict: store+load alias
                                                    int nmols) {
    const int lane = threadIdx.x & 63;
    const int half = lane >> 5;      // 0/1
    const int hl = lane & 31;        // lane within half-wave
    const int wave = (blockIdx.x * 256 + threadIdx.x) >> 6;   // 0..8191
    const float sc = 0.08838834764831845f;  // 1/sqrt(128)

    for (int si = 0; si < 2; ++si) {
        int s = wave * 2 + si;
        if (s >= nmols) break;
        int s0 = start[s], s1 = start[s + 1];
        if (s0 >= s1) continue;

        f32x4 rfrag = *((const f32x4*)(R + (long)s * 128) + hl);

        float mx = -__builtin_inff();
        float sum = 0.f;
        int kb = s0;

        f32x4 a0, a1, a2, a3;
        bool have = (kb + 8 <= s1);
        if (have) {
            long k = kb + half;
            a0 = __builtin_nontemporal_load((const f32x4*)(K + (k + 0) * 128) + hl);
            a1 = __builtin_nontemporal_load((const f32x4*)(K + (k + 2) * 128) + hl);
            a2 = __builtin_nontemporal_load((const f32x4*)(K + (k + 4) * 128) + hl);
            a3 = __builtin_nontemporal_load((const f32x4*)(K + (k + 6) * 128) + hl);
        }
        while (have) {
            bool havenext = (kb + 16 <= s1);
            f32x4 b0, b1, b2, b3;
            if (havenext) {
                long kn = kb + 8 + half;
                b0 = __builtin_nontemporal_load((const f32x4*)(K + (kn + 0) * 128) + hl);
                b1 = __builtin_nontemporal_load((const f32x4*)(K + (kn + 2) * 128) + hl);
                b2 = __builtin_nontemporal_load((const f32x4*)(K + (kn + 4) * 128) + hl);
                b3 = __builtin_nontemporal_load((const f32x4*)(K + (kn + 6) * 128) + hl);
            }
            float v0 = dot4(a0, rfrag);
            float v1 = dot4(a1, rfrag);
            float v2 = dot4(a2, rfrag);
            float v3 = dot4(a3, rfrag);
#pragma unroll
            for (int off = 16; off > 0; off >>= 1) {
                v0 += __shfl_xor(v0, off, 64);
                v1 += __shfl_xor(v1, off, 64);
                v2 += __shfl_xor(v2, off, 64);
                v3 += __shfl_xor(v3, off, 64);
            }
            v0 *= sc; v1 *= sc; v2 *= sc; v3 *= sc;
            long k = kb + half;
            if (hl == 0) {
                scores[k + 0] = v0;
                scores[k + 2] = v1;
                scores[k + 4] = v2;
                scores[k + 6] = v3;
            }
            float bm = fmaxf(fmaxf(v0, v1), fmaxf(v2, v3));
            float nm = fmaxf(mx, bm);
            sum = sum * __expf(mx - nm)
                + __expf(v0 - nm) + __expf(v1 - nm)
                + __expf(v2 - nm) + __expf(v3 - nm);
            mx = nm;
            kb += 8;
            a0 = b0; a1 = b1; a2 = b2; a3 = b3;
            have = havenext;
        }
        for (long k = kb + half; k < s1; k += 2) {
            f32x4 kv = __builtin_nontemporal_load((const f32x4*)(K + k * 128) + hl);
            float v = dot4(kv, rfrag);
#pragma unroll
            for (int off = 16; off > 0; off >>= 1) v += __shfl_xor(v, off, 64);
            v *= sc;
            if (hl == 0) scores[k] = v;
            float nm = fmaxf(mx, v);
            sum = sum * __expf(mx - nm) + __expf(v - nm);
            mx = nm;
        }
        float mo = __shfl_xor(mx, 32, 64);
        float so = __shfl_xor(sum, 32, 64);
        float nm = fmaxf(mx, mo);
        sum = sum * __expf(mx - nm) + so * __expf(mo - nm);
        mx = nm;
        float inv = 1.0f / sum;

        asm volatile("s_waitcnt vmcnt(0)" ::: "memory");

        for (int i = s0 + lane; i < s1; i += 64)
            weights[i] = __expf(scores[i] - mx) * inv;
    }
}

// ---------------------------------------------------------------------------
// CONTROL: pure K read with the fused kernel's exact access pattern.
// wave w owns rows [w*128, w*128+128); per iter 4 NT f32x4 loads/lane
// (rows kb..kb+7 across the two halves), accumulate, per-lane 4B sum to ws.
// ---------------------------------------------------------------------------
__global__ __launch_bounds__(256) void stream_kernel(const float* __restrict__ K,
                                                     float* __restrict__ out,
                                                     int total) {
    const int lane = threadIdx.x & 63;
    const int half = lane >> 5;
    const int hl = lane & 31;
    const int wave = (blockIdx.x * 256 + threadIdx.x) >> 6;   // 0..8191
    const int nwaves = gridDim.x * 4;
    const int rpw = (total + nwaves - 1) / nwaves;            // 128

    long s0 = (long)wave * rpw;
    long s1 = s0 + rpw;
    if (s1 > total) s1 = total;

    f32x4 acc = {0.f, 0.f, 0.f, 0.f};
    for (long kb = s0; kb + 8 <= s1; kb += 8) {
        long k = kb + half;
        f32x4 a0 = __builtin_nontemporal_load((const f32x4*)(K + (k + 0) * 128) + hl);
        f32x4 a1 = __builtin_nontemporal_load((const f32x4*)(K + (k + 2) * 128) + hl);
        f32x4 a2 = __builtin_nontemporal_load((const f32x4*)(K + (k + 4) * 128) + hl);
        f32x4 a3 = __builtin_nontemporal_load((const f32x4*)(K + (k + 6) * 128) + hl);
        acc += a0 + a1 + a2 + a3;
    }
    out[(long)wave * 64 + lane] = acc.x + acc.y + acc.z + acc.w;
}

// ---------------------------------------------------------------------------
extern "C" void kernel_launch(void* const* d_in, const int* in_sizes, int n_in,
                              void* d_out, int out_size, void* d_ws, size_t ws_size,
                              hipStream_t stream) {
    const float* Q   = (const float*)d_in[0];
    const float* K   = (const float*)d_in[1];
    const float* WQ  = (const float*)d_in[2];
    const float* WK  = (const float*)d_in[3];
    const int*   idx = (const int*)d_in[4];

    const int nmols = in_sizes[0] / QUERY_DIM;   // 16384
    const int total = in_sizes[4];               // 1048576

    float* weights = (float*)d_out;              // output 0
    float* scores  = (float*)d_out + total;      // output 1

    char* ws = (char*)d_ws;
    float* W         = (float*)ws;                        // 64 KB
    int*   segstart  = (int*)(ws + 65536);                // (nmols+1)*4
    float* R         = (float*)(ws + 65536 + 131072);     // nmols*128*4 = 8 MB
    float* streamout = (float*)(ws + (16u << 20));        // control sums (2 MB)

    int segblocks = (nmols + 1 + 255) / 256;
    combo_kernel<<<64 + segblocks, 256, 0, stream>>>(WQ, WK, W, idx, segstart, nmols, total);
    qproj_kernel<<<(nmols + 15) / 16, 256, 0, stream>>>(Q, W, R, nmols);
    fused_kernel<<<2048, 256, 0, stream>>>(K, R, segstart, weights, scores, nmols);
    // control: T_stream = dur - 138.5us
    stream_kernel<<<2048, 256, 0, stream>>>(K, streamout, total);
}